// Round 1
// baseline (30.663 us; speedup 1.0000x reference)
//
#include <hip/hip_runtime.h>

// Problem constants (from the reference file)
#define GN_NODES   1000000
#define GN_TPB     256
#define GN_NBLOCKS 1024

// ---------------------------------------------------------------------------
// Kernel 1: streaming reduction of cart [NODES,3] and neigh [NODES,4,2].
// Produces 5 partial sums per block: Scart_x, Scart_y, Scart_z, Sn0, Sn1.
// Layout in ws: partials[c * gridDim.x + blockIdx.x], c in 0..4.
// ---------------------------------------------------------------------------
__global__ __launch_bounds__(GN_TPB) void gn_reduce(
    const float* __restrict__ cart,
    const float* __restrict__ neigh,
    float* __restrict__ partials)
{
    const int tid = blockIdx.x * GN_TPB + threadIdx.x;
    const int T   = gridDim.x * GN_TPB;

    float sx = 0.f, sy = 0.f, sz = 0.f, s0 = 0.f, s1 = 0.f;

    // cart: 3,000,000 floats = 250,000 chunks of 12 floats (4 nodes).
    // Within a 12-float chunk the component pattern is x y z x y z x y z x y z.
    const float4* cart4 = reinterpret_cast<const float4*>(cart);
    for (int c = tid; c < 250000; c += T) {
        float4 a = cart4[3 * c + 0];
        float4 b = cart4[3 * c + 1];
        float4 d = cart4[3 * c + 2];
        sx += a.x + a.w + b.z + d.y;
        sy += a.y + b.x + b.w + d.z;
        sz += a.z + b.y + d.x + d.w;
    }

    // neigh: 8,000,000 floats = 2,000,000 float4; components alternate 0,1,0,1.
    const float4* n4 = reinterpret_cast<const float4*>(neigh);
    for (int i = tid; i < 2000000; i += T) {
        float4 v = n4[i];
        s0 += v.x + v.z;
        s1 += v.y + v.w;
    }

    // Wave (64-lane) butterfly reduce.
    for (int o = 32; o > 0; o >>= 1) {
        sx += __shfl_down(sx, o);
        sy += __shfl_down(sy, o);
        sz += __shfl_down(sz, o);
        s0 += __shfl_down(s0, o);
        s1 += __shfl_down(s1, o);
    }

    __shared__ float red[5][GN_TPB / 64];
    const int wave = threadIdx.x >> 6;
    if ((threadIdx.x & 63) == 0) {
        red[0][wave] = sx; red[1][wave] = sy; red[2][wave] = sz;
        red[3][wave] = s0; red[4][wave] = s1;
    }
    __syncthreads();
    if (threadIdx.x == 0) {
        const int nb = gridDim.x;
        #pragma unroll
        for (int c = 0; c < 5; ++c) {
            float s = red[c][0];
            #pragma unroll
            for (int w = 1; w < GN_TPB / 64; ++w) s += red[c][w];
            partials[c * nb + blockIdx.x] = s;
        }
    }
}

// ---------------------------------------------------------------------------
// Kernel 2: reduce the per-block partials, then one thread applies the whole
// (affine) network to the sums in fp64 and writes the scalar output.
// ---------------------------------------------------------------------------
__global__ __launch_bounds__(256) void gn_finish(
    const float* __restrict__ partials, int nblocks,
    const float* __restrict__ Wc1,  const float* __restrict__ bc1,
    const float* __restrict__ Wc2,  const float* __restrict__ bc2,
    const float* __restrict__ Wn1,  const float* __restrict__ bn1,
    const float* __restrict__ Wn2,  const float* __restrict__ bn2,
    const float* __restrict__ Wcomb, const float* __restrict__ bcomb,
    const float* __restrict__ Wdeco, const float* __restrict__ bdeco,
    const int* __restrict__ kptr,
    float* __restrict__ out)
{
    __shared__ float totals[5];
    __shared__ float red[4];

    for (int c = 0; c < 5; ++c) {
        float s = 0.f;
        for (int i = threadIdx.x; i < nblocks; i += 256)
            s += partials[c * nblocks + i];
        for (int o = 32; o > 0; o >>= 1) s += __shfl_down(s, o);
        if ((threadIdx.x & 63) == 0) red[threadIdx.x >> 6] = s;
        __syncthreads();
        if (threadIdx.x == 0) totals[c] = red[0] + red[1] + red[2] + red[3];
        __syncthreads();
    }

    if (threadIdx.x == 0) {
        const double NN = (double)GN_NODES;
        const double Sc0 = totals[0], Sc1 = totals[1], Sc2 = totals[2];
        const double Sn0 = totals[3], Sn1 = totals[4];

        // H = sum over nodes of h = (cart @ Wc1^T + bc1) @ Wc2^T + bc2
        double t[10], H[10];
        for (int p = 0; p < 10; ++p)
            t[p] = (double)Wc1[p * 3 + 0] * Sc0 + (double)Wc1[p * 3 + 1] * Sc1 +
                   (double)Wc1[p * 3 + 2] * Sc2 + NN * (double)bc1[p];
        for (int i = 0; i < 10; ++i) {
            double s = NN * (double)bc2[i];
            for (int p = 0; p < 10; ++p) s += (double)Wc2[i * 10 + p] * t[p];
            H[i] = s;
        }

        // Mv = sum over nodes of m = mean_j (neigh @ Wn1^T + bn1) @ Wn2^T + bn2
        double u[10], Mv[10];
        for (int p = 0; p < 10; ++p)
            u[p] = (double)Wn1[p * 2 + 0] * (Sn0 * 0.25) +
                   (double)Wn1[p * 2 + 1] * (Sn1 * 0.25) + NN * (double)bn1[p];
        for (int i = 0; i < 10; ++i) {
            double s = NN * (double)bn2[i];
            for (int p = 0; p < 10; ++p) s += (double)Wn2[i * 10 + p] * u[p];
            Mv[i] = s;
        }

        // k rounds of comb: C = [Mv, S] @ Wcomb^T + NODES*bcomb, S <- C
        const int k = *kptr;
        double S[10], C[10];
        for (int i = 0; i < 10; ++i) S[i] = H[i];
        for (int it = 0; it < k; ++it) {
            for (int i = 0; i < 10; ++i) {
                double s = NN * (double)bcomb[i];
                for (int p = 0; p < 10; ++p) {
                    s += (double)Wcomb[i * 20 + p]      * Mv[p];
                    s += (double)Wcomb[i * 20 + 10 + p] * S[p];
                }
                C[i] = s;
            }
            for (int i = 0; i < 10; ++i) S[i] = C[i];
        }

        // decode: out = S @ Wdeco^T + bdeco
        double o = (double)bdeco[0];
        for (int i = 0; i < 10; ++i) o += (double)Wdeco[i] * S[i];
        out[0] = (float)o;
    }
}

extern "C" void kernel_launch(void* const* d_in, const int* in_sizes, int n_in,
                              void* d_out, int out_size, void* d_ws, size_t ws_size,
                              hipStream_t stream) {
    const float* cart  = (const float*)d_in[0];
    const float* neigh = (const float*)d_in[1];
    const float* Wc1   = (const float*)d_in[2];
    const float* bc1   = (const float*)d_in[3];
    const float* Wc2   = (const float*)d_in[4];
    const float* bc2   = (const float*)d_in[5];
    const float* Wn1   = (const float*)d_in[6];
    const float* bn1   = (const float*)d_in[7];
    const float* Wn2   = (const float*)d_in[8];
    const float* bn2   = (const float*)d_in[9];
    const float* Wcomb = (const float*)d_in[10];
    const float* bcomb = (const float*)d_in[11];
    const float* Wdeco = (const float*)d_in[12];
    const float* bdeco = (const float*)d_in[13];
    const int*   kptr  = (const int*)d_in[14];

    float* partials = (float*)d_ws;  // 5 * GN_NBLOCKS floats = 20 KB

    gn_reduce<<<GN_NBLOCKS, GN_TPB, 0, stream>>>(cart, neigh, partials);
    gn_finish<<<1, 256, 0, stream>>>(partials, GN_NBLOCKS,
                                     Wc1, bc1, Wc2, bc2,
                                     Wn1, bn1, Wn2, bn2,
                                     Wcomb, bcomb, Wdeco, bdeco,
                                     kptr, (float*)d_out);
}